// Round 12
// baseline (189.722 us; speedup 1.0000x reference)
//
#include <hip/hip_runtime.h>

#define THREADS 512            // 8 waves/block; 1 block/CU (128 KB LDS)
#define ROWS    128            // rows per block
#define BINS    512
#define WORDS   128            // u8-packed: 4 bins per u32 word
#define LO      (-0.6f)
#define RANGE   (1.3f)

typedef short bf16x8 __attribute__((ext_vector_type(8)));
typedef float f32x4  __attribute__((ext_vector_type(4)));

// fp32 -> bf16 with round-to-nearest-even
__device__ __forceinline__ short f2bf(float f) {
    unsigned int u = __builtin_bit_cast(unsigned int, f);
    u = (u + 0x7FFFu + ((u >> 16) & 1u)) >> 16;
    return (short)u;
}

// pre-pass: fp32 X -> bf16 (one float4 per thread)
__global__ __launch_bounds__(256)
void cvt_kernel(const float* __restrict__ X, short* __restrict__ Xb) {
    int i = blockIdx.x * 256 + threadIdx.x;   // 0 .. 2097151
    float4 v = ((const float4*)X)[i];
    short4 s = { f2bf(v.x), f2bf(v.y), f2bf(v.z), f2bf(v.w) };
    ((short4*)Xb)[i] = s;
}

// R12 (= R11 with legal waitcnt): DS-queue ordering discipline. LDS ops
// complete IN ORDER per wave, so R10's "lgkmcnt(0) after ds_read" also
// drained the 16 atomics fired just before it (contended DS pipe -> ~600-900
// cy stall per wave-tile). Order per tile: lgkm(15) [prev reads + 1 stale
// atomic done, 15 atomics pending OK] -> stage -> MFMA -> binsV(regs) ->
// vmcnt(0) -> ds_read -> binsA(atomics last). A wave never waits on a fresh
// atomic; reads always precede atomics in the queue. lgkmcnt is a 4-bit
// field (max 15) -- R11's lgkmcnt(16) did not assemble.
__global__ __launch_bounds__(THREADS, 2)   // 8 waves = 2/SIMD; cap 256
void scpp_kernel(const short* __restrict__ X, float* __restrict__ out) {
    extern __shared__ char smem[];          // [0,64K) hist  [64K,128K) slabs
    unsigned int* hist = (unsigned int*)smem;

    const int t    = threadIdx.x;
    const int wave = t >> 6;           // 0..7
    const int lane = t & 63;
    const int q    = lane >> 4;        // quad 0..3
    const int ln   = lane & 15;
    const int h    = wave >> 2;        // row-half: rows m0 + h*64 .. +63
    const int cg   = wave & 3;         // col-group: cols nt*64 + cg*16 .. +15
    const int bid  = blockIdx.x;       // 0..255 -> 1 block/CU, zero tail
    const int batch = bid & 7;         // XCD-batch pinning
    const int m0    = (bid >> 3) * ROWS;
    const short* Xb = X + (size_t)batch * 4096 * 256;

    char* slab = smem + 65536 + wave * 8192;   // private per-wave slab

    // zero histograms: 16384 words / 512 threads
    #pragma unroll
    for (int i = 0; i < (ROWS * WORDS) / THREADS; ++i)
        hist[t + THREADS * i] = 0u;

    // A fragments: 4 strips of 16 rows within this wave's row-half.
    bf16x8 af[4][8];
    {
        #pragma unroll
        for (int s = 0; s < 4; ++s) {
            const short* ap = Xb + (size_t)(m0 + h * 64 + s * 16 + ln) * 256 + q * 8;
            #pragma unroll
            for (int ks = 0; ks < 8; ++ks)
                af[s][ks] = *(const bf16x8*)(ap + ks * 32);
        }
        #pragma unroll
        for (int s = 0; s < 4; ++s)
            #pragma unroll
            for (int ks = 0; ks < 8; ++ks)
                asm volatile("" : "+v"(af[s][ks]));   // opaque: blocks remat
    }

    // stage this wave's 16 cols of tile nt into its private slab (8 x 1KB)
    auto stage = [&](int nt) {
        #pragma unroll
        for (int i = 0; i < 8; ++i) {
            int c = 2 * i + (lane >> 5);                  // slab col 0..15
            int r = ((lane & 31) << 4) ^ ((c & 7) << 4);  // pre-swizzled byte
            const short* src = Xb + (size_t)(nt * 64 + cg * 16 + c) * 256 + (r >> 1);
            __builtin_amdgcn_global_load_lds(
                (const __attribute__((address_space(1))) void*)src,
                (__attribute__((address_space(3))) void*)(slab + i * 1024),
                16, 0, 0);
        }
    };

    stage(0);
    __syncthreads();   // hist zeros visible; prologue DMA drained (full drain)

    // bin transform: b = (v/256 - LO) * BINS/RANGE == v*scale + off
    const float scale = ((float)BINS / RANGE) / 256.0f;
    const float off   = -LO * ((float)BINS / RANGE);

    // loop-invariant per-strip histogram row pointer + bank swizzle
    unsigned int* Hrow[4];
    unsigned      swzr[4];
    #pragma unroll
    for (int s = 0; s < 4; ++s) {
        int row = h * 64 + s * 16 + ln;
        Hrow[s] = &hist[row * WORDS];
        swzr[s] = (unsigned)((row * 9) & 31);
    }

    const int lnx = (ln & 7) << 4;     // read-side swizzle (col = ln in slab)

    // prologue reads: bb(0) from slab (DMA drained by the barrier above)
    bf16x8 bb[8];
    #pragma unroll
    for (int ks = 0; ks < 8; ++ks)
        bb[ks] = *(const bf16x8*)(slab + ln * 512 + ((ks * 64 + q * 16) ^ lnx));

    for (int nt = 0; nt < 64; ++nt) {
        if (nt > 0) {
            // Drain to <=15 outstanding: the 8 prev reads (+1 stale atomic)
            // complete; 15 fresh atomics may remain in flight. Must precede
            // stage(): DMA may not overwrite slab words still being read.
            asm volatile("s_waitcnt lgkmcnt(15)" ::: "memory");
            __builtin_amdgcn_sched_barrier(0);
        }
        if (nt + 1 < 64) stage(nt + 1);   // DMA flight hides under MFMA+binsV

        f32x4 acc[4];
        #pragma unroll
        for (int s = 0; s < 4; ++s) acc[s] = f32x4{0.f, 0.f, 0.f, 0.f};
        __builtin_amdgcn_s_setprio(1);
        #pragma unroll
        for (int ks = 0; ks < 8; ++ks)
            #pragma unroll
            for (int s = 0; s < 4; ++s)   // swapped: bb as A, af as B -> D^T
                acc[s] = __builtin_amdgcn_mfma_f32_16x16x32_bf16(bb[ks], af[s][ks], acc[s], 0, 0, 0);
        __builtin_amdgcn_s_setprio(0);

        // binsV: bin indices to registers (no DS ops yet)
        int bv[4][4];
        #pragma unroll
        for (int s = 0; s < 4; ++s)
            #pragma unroll
            for (int reg = 0; reg < 4; ++reg)
                bv[s][reg] = (int)__builtin_amdgcn_fmed3f(
                                 acc[s][reg] * scale + off, 0.0f, 511.0f);

        if (nt + 1 < 64) {
            asm volatile("s_waitcnt vmcnt(0)" ::: "memory");   // stage landed
            __builtin_amdgcn_sched_barrier(0);
            #pragma unroll
            for (int ks = 0; ks < 8; ++ks)   // reads FIRST in DS queue
                bb[ks] = *(const bf16x8*)(slab + ln * 512 + ((ks * 64 + q * 16) ^ lnx));
            __builtin_amdgcn_sched_barrier(0);   // pin: atomics stay after reads
        }

        // binsA: 16 fire-and-forget atomics (newest in queue; never waited on)
        #pragma unroll
        for (int s = 0; s < 4; ++s)
            #pragma unroll
            for (int reg = 0; reg < 4; ++reg) {
                int b  = bv[s][reg];
                int pw = (b >> 2) ^ swzr[s];
                atomicAdd(&Hrow[s][pw], 1u << ((b & 3) << 3));
            }
    }
    __syncthreads();   // full drain: all waves' atomics visible

    // epilogue, in-register per wave: rows 16w .. 16w+15 (u8 unpack)
    const float binw = RANGE / (float)BINS;
    #pragma unroll
    for (int rr = 0; rr < 16; ++rr) {
        const int r = wave * 16 + rr;
        const unsigned int msk = (unsigned int)(r * 9) & 31u;
        const unsigned int* H = &hist[r * WORDS];
        // lane L holds logical words 2L..2L+1 = bins 8L..8L+7 (un-swizzle)
        int cnt[8];
        #pragma unroll
        for (int i2 = 0; i2 < 2; ++i2) {
            unsigned int wd = H[(unsigned int)(2 * lane + i2) ^ msk];
            cnt[4 * i2 + 0] = (int)(wd & 0xFFu);
            cnt[4 * i2 + 1] = (int)((wd >> 8)  & 0xFFu);
            cnt[4 * i2 + 2] = (int)((wd >> 16) & 0xFFu);
            cnt[4 * i2 + 3] = (int)((wd >> 24) & 0xFFu);
        }
        int local = 0;
        #pragma unroll
        for (int u = 0; u < 8; ++u) local += cnt[u];
        // suffix-sum over lanes
        int suf = local;
        #pragma unroll
        for (int o2 = 1; o2 < 64; o2 <<= 1) {
            int o = __shfl_down(suf, o2, 64);
            if (lane + o2 < 64) suf += o;
        }
        int run = suf - local;
        int s[8];                       // s[u] = S[8*lane+u] = #values >= edge
        #pragma unroll
        for (int u = 7; u >= 0; --u) { run += cnt[u]; s[u] = run; }

        // answer 256 queries for this row: lane handles i = qq*64 + lane
        #pragma unroll
        for (int qq = 0; qq < 4; ++qq) {
            int i = qq * 64 + lane;
            float rv = 1.0f + (float)i * (4094.0f / 255.0f);
            int k = (int)rintf(rv) + 1;   // k-th largest, k in [2, 4096]
            int Lo = 0;
            #pragma unroll
            for (int st = 32; st >= 1; st >>= 1) {
                int cand = Lo + st;       // always <= 63
                int v = __shfl(s[0], cand, 64);
                if (v >= k) Lo = cand;
            }
            int j8 = 0;
            #pragma unroll
            for (int u = 0; u < 8; ++u) {
                int v = __shfl(s[u], Lo, 64);
                j8 += (v >= k) ? 1 : 0;
            }
            int j = 8 * Lo + j8 - 1;
            out[(size_t)(batch * 4096 + m0 + r) * 256 + i] = LO + ((float)j + 0.5f) * binw;
        }
    }
}

extern "C" void kernel_launch(void* const* d_in, const int* in_sizes, int n_in,
                              void* d_out, int out_size, void* d_ws, size_t ws_size,
                              hipStream_t stream) {
    static int attr_set = 0;
    if (!attr_set) {   // one-time, host-side, not a stream op (capture-safe)
        (void)hipFuncSetAttribute((const void*)scpp_kernel,
                                  hipFuncAttributeMaxDynamicSharedMemorySize, 131072);
        attr_set = 1;
    }
    const float* x = (const float*)d_in[0];
    float* out = (float*)d_out;
    const size_t nelem = (size_t)8 * 4096 * 256;          // 8,388,608
    short* xb = (short*)d_ws;
    hipLaunchKernelGGL(cvt_kernel, dim3(nelem / 1024), dim3(256), 0, stream, x, xb);
    hipLaunchKernelGGL(scpp_kernel, dim3(256), dim3(THREADS), 131072, stream, xb, out);
}

// Round 13
// 173.774 us; speedup vs baseline: 1.0918x; 1.0918x over previous
//
#include <hip/hip_runtime.h>

#define THREADS 512            // 8 waves/block; 1 block/CU
#define ROWS    128            // rows per block
#define BINS    512
#define WORDS   128            // u8-packed: 4 bins per u32 word
#define LO      (-0.6f)
#define RANGE   (1.3f)

typedef short bf16x8 __attribute__((ext_vector_type(8)));
typedef float f32x4  __attribute__((ext_vector_type(4)));

// fp32 -> bf16 with round-to-nearest-even
__device__ __forceinline__ short f2bf(float f) {
    unsigned int u = __builtin_bit_cast(unsigned int, f);
    u = (u + 0x7FFFu + ((u >> 16) & 1u)) >> 16;
    return (short)u;
}

// R13 cvt: fp32 -> bf16 into a FRAGMENT-BLOCKED layout so every MFMA operand
// load in scpp is one fully-coalesced dwordx4 at base+lane*16B.
//   blk_shorts(b, p, c) = (b<<20) + g*4096 + ks*512 + kq*128 + ln*8 + ci
//   g=p>>4, ln=p&15, ks=c>>5, kq=(c>>3)&3, ci=c&7
// Thread (b,g,ks,lane) with lane=(kq,ln): reads 8 fp32, writes 16B coalesced.
__global__ __launch_bounds__(256)
void cvt_kernel(const float* __restrict__ X, short* __restrict__ Xb) {
    int i    = blockIdx.x * 256 + threadIdx.x;   // 0 .. 2^20-1
    int lane = i & 63;
    int ks   = (i >> 6) & 7;
    int g    = (i >> 9) & 255;
    int b    = i >> 17;
    int ln   = lane & 15, kq = lane >> 4;
    const float* src = X + ((size_t)(b * 4096 + g * 16 + ln) * 256 + ks * 32 + kq * 8);
    float4 v0 = ((const float4*)src)[0];
    float4 v1 = ((const float4*)src)[1];
    bf16x8 o;
    o[0] = f2bf(v0.x); o[1] = f2bf(v0.y); o[2] = f2bf(v0.z); o[3] = f2bf(v0.w);
    o[4] = f2bf(v1.x); o[5] = f2bf(v1.y); o[6] = f2bf(v1.z); o[7] = f2bf(v1.w);
    *(bf16x8*)(Xb + ((size_t)b << 20) + g * 4096 + ks * 512 + lane * 8) = o;
}

// R13 scpp: NO LDS slab. B fragments load straight to registers from the
// blocked layout (coalesced); DS pipe carries ONLY histogram atomics.
// R10-R12 lesson: DS-pipe occupancy (reads+DMA+atomics ~66% of tile) was the
// wall, not wait placement -- so remove the reads and DMA writes.
__global__ __launch_bounds__(THREADS, 2)   // 8 waves = 2/SIMD; cap 256
void scpp_kernel(const short* __restrict__ X, float* __restrict__ out) {
    extern __shared__ unsigned int hist[];   // 16384 words = 64 KB

    const int t    = threadIdx.x;
    const int wave = t >> 6;           // 0..7
    const int lane = t & 63;
    const int q    = lane >> 4;        // quad 0..3
    const int ln   = lane & 15;
    const int h    = wave >> 2;        // row-half: rows m0 + h*64 .. +63
    const int cg   = wave & 3;         // col-group: cols nt*64 + cg*16 .. +15
    const int bid  = blockIdx.x;       // 0..255 -> 1 block/CU, zero tail
    const int batch = bid & 7;         // XCD-batch pinning
    const int m0    = (bid >> 3) * ROWS;
    const short* Xb = X + ((size_t)batch << 20);

    // zero histograms: 16384 words / 512 threads
    #pragma unroll
    for (int i = 0; i < (ROWS * WORDS) / THREADS; ++i)
        hist[t + THREADS * i] = 0u;

    // A fragments: 4 strips of 16 rows; coalesced fragment loads.
    bf16x8 af[4][8];
    {
        #pragma unroll
        for (int s = 0; s < 4; ++s) {
            const short* ap = Xb + (size_t)((m0 >> 4) + h * 4 + s) * 4096 + lane * 8;
            #pragma unroll
            for (int ks = 0; ks < 8; ++ks)
                af[s][ks] = *(const bf16x8*)(ap + ks * 512);
        }
        #pragma unroll
        for (int s = 0; s < 4; ++s)
            #pragma unroll
            for (int ks = 0; ks < 8; ++ks)
                asm volatile("" : "+v"(af[s][ks]));   // opaque: blocks remat
    }
    __syncthreads();   // hist zeros visible before atomics

    // bin transform: b = (v/256 - LO) * BINS/RANGE == v*scale + off
    const float scale = ((float)BINS / RANGE) / 256.0f;
    const float off   = -LO * ((float)BINS / RANGE);

    // loop-invariant per-strip histogram row pointer + bank swizzle
    // (lane ln owns row h*64 + s*16 + ln via the swapped-operand MFMA)
    unsigned int* Hrow[4];
    unsigned      swzr[4];
    #pragma unroll
    for (int s = 0; s < 4; ++s) {
        int row = h * 64 + s * 16 + ln;
        Hrow[s] = &hist[row * WORDS];
        swzr[s] = (unsigned)((row * 9) & 31);
    }

    // B fragment base for tile nt (coalesced: base + lane*16B)
    auto bptr = [&](int nt) {
        return Xb + (size_t)(nt * 4 + cg) * 4096 + lane * 8;
    };
    auto load4 = [&](bf16x8* d, const short* p, int ks0) {
        #pragma unroll
        for (int j = 0; j < 4; ++j)
            d[j] = *(const bf16x8*)(p + (ks0 + j) * 512);
    };

    auto mfma_half = [&](f32x4* acc, const bf16x8* bx, int ks0) {
        __builtin_amdgcn_s_setprio(1);
        #pragma unroll
        for (int j = 0; j < 4; ++j)
            #pragma unroll
            for (int s = 0; s < 4; ++s)   // swapped: bb as A, af as B -> D^T
                acc[s] = __builtin_amdgcn_mfma_f32_16x16x32_bf16(bx[j], af[s][ks0 + j], acc[s], 0, 0, 0);
        __builtin_amdgcn_s_setprio(0);
    };
    auto bins = [&](const f32x4* acc) {
        int bv[4][4];
        #pragma unroll
        for (int s = 0; s < 4; ++s)
            #pragma unroll
            for (int reg = 0; reg < 4; ++reg)
                bv[s][reg] = (int)__builtin_amdgcn_fmed3f(
                                 acc[s][reg] * scale + off, 0.0f, 511.0f);
        #pragma unroll
        for (int s = 0; s < 4; ++s)
            #pragma unroll
            for (int reg = 0; reg < 4; ++reg) {
                int b  = bv[s][reg];
                int pw = (b >> 2) ^ swzr[s];
                atomicAdd(&Hrow[s][pw], 1u << ((b & 3) << 3));
            }
    };

    // K-loop: register ping-pong in tile halves (static names, rule #20);
    // plain C++ loads -- compiler-tracked waitcnt, software-pipelined.
    bf16x8 bA0[4], bB0[4], bA1[4], bB1[4];
    load4(bA0, bptr(0), 0);
    load4(bB0, bptr(0), 4);
    for (int nt = 0; nt < 64; nt += 2) {
        const short* p1 = bptr(nt + 1);
        const short* p2 = bptr(nt + 2 < 64 ? nt + 2 : 63);
        f32x4 acc[4];
        // even tile (bA0/bB0), prefetch odd into bA1/bB1
        #pragma unroll
        for (int s = 0; s < 4; ++s) acc[s] = f32x4{0.f, 0.f, 0.f, 0.f};
        load4(bA1, p1, 0);
        mfma_half(acc, bA0, 0);
        load4(bB1, p1, 4);
        mfma_half(acc, bB0, 4);
        bins(acc);
        // odd tile (bA1/bB1), prefetch next-even into bA0/bB0
        #pragma unroll
        for (int s = 0; s < 4; ++s) acc[s] = f32x4{0.f, 0.f, 0.f, 0.f};
        load4(bA0, p2, 0);
        mfma_half(acc, bA1, 0);
        load4(bB0, p2, 4);
        mfma_half(acc, bB1, 4);
        bins(acc);
    }
    __syncthreads();   // all waves' atomics visible

    // epilogue, in-register per wave: rows 16w .. 16w+15 (u8 unpack)
    const float binw = RANGE / (float)BINS;
    #pragma unroll
    for (int rr = 0; rr < 16; ++rr) {
        const int r = wave * 16 + rr;
        const unsigned int msk = (unsigned int)(r * 9) & 31u;
        const unsigned int* H = &hist[r * WORDS];
        // lane L holds logical words 2L..2L+1 = bins 8L..8L+7 (un-swizzle)
        int cnt[8];
        #pragma unroll
        for (int i2 = 0; i2 < 2; ++i2) {
            unsigned int wd = H[(unsigned int)(2 * lane + i2) ^ msk];
            cnt[4 * i2 + 0] = (int)(wd & 0xFFu);
            cnt[4 * i2 + 1] = (int)((wd >> 8)  & 0xFFu);
            cnt[4 * i2 + 2] = (int)((wd >> 16) & 0xFFu);
            cnt[4 * i2 + 3] = (int)((wd >> 24) & 0xFFu);
        }
        int local = 0;
        #pragma unroll
        for (int u = 0; u < 8; ++u) local += cnt[u];
        // suffix-sum over lanes
        int suf = local;
        #pragma unroll
        for (int o2 = 1; o2 < 64; o2 <<= 1) {
            int o = __shfl_down(suf, o2, 64);
            if (lane + o2 < 64) suf += o;
        }
        int run = suf - local;
        int s[8];                       // s[u] = S[8*lane+u] = #values >= edge
        #pragma unroll
        for (int u = 7; u >= 0; --u) { run += cnt[u]; s[u] = run; }

        // answer 256 queries for this row: lane handles i = qq*64 + lane
        #pragma unroll
        for (int qq = 0; qq < 4; ++qq) {
            int i = qq * 64 + lane;
            float rv = 1.0f + (float)i * (4094.0f / 255.0f);
            int k = (int)rintf(rv) + 1;   // k-th largest, k in [2, 4096]
            int Lo = 0;
            #pragma unroll
            for (int st = 32; st >= 1; st >>= 1) {
                int cand = Lo + st;       // always <= 63
                int v = __shfl(s[0], cand, 64);
                if (v >= k) Lo = cand;
            }
            int j8 = 0;
            #pragma unroll
            for (int u = 0; u < 8; ++u) {
                int v = __shfl(s[u], Lo, 64);
                j8 += (v >= k) ? 1 : 0;
            }
            int j = 8 * Lo + j8 - 1;
            out[(size_t)(batch * 4096 + m0 + r) * 256 + i] = LO + ((float)j + 0.5f) * binw;
        }
    }
}

extern "C" void kernel_launch(void* const* d_in, const int* in_sizes, int n_in,
                              void* d_out, int out_size, void* d_ws, size_t ws_size,
                              hipStream_t stream) {
    static int attr_set = 0;
    if (!attr_set) {   // one-time, host-side, not a stream op (capture-safe)
        (void)hipFuncSetAttribute((const void*)scpp_kernel,
                                  hipFuncAttributeMaxDynamicSharedMemorySize, 65536);
        attr_set = 1;
    }
    const float* x = (const float*)d_in[0];
    float* out = (float*)d_out;
    short* xb = (short*)d_ws;                              // 16 MB blocked bf16
    hipLaunchKernelGGL(cvt_kernel, dim3(4096), dim3(256), 0, stream, x, xb);
    hipLaunchKernelGGL(scpp_kernel, dim3(256), dim3(THREADS), 65536, stream, xb, out);
}

// Round 14
// 173.542 us; speedup vs baseline: 1.0932x; 1.0013x over previous
//
#include <hip/hip_runtime.h>

#define THREADS 512            // 8 waves/block; 1 block/CU
#define ROWS    128            // rows per block
#define BINS    512
#define WORDS   128            // u8-packed: 4 bins per u32 word
#define LO      (-0.6f)
#define RANGE   (1.3f)

typedef short bf16x8 __attribute__((ext_vector_type(8)));
typedef float f32x4  __attribute__((ext_vector_type(4)));

// fp32 -> bf16 with round-to-nearest-even
__device__ __forceinline__ short f2bf(float f) {
    unsigned int u = __builtin_bit_cast(unsigned int, f);
    u = (u + 0x7FFFu + ((u >> 16) & 1u)) >> 16;
    return (short)u;
}

// cvt: fp32 -> bf16 into the FRAGMENT-BLOCKED layout (R13) so every MFMA
// operand load in scpp is one fully-coalesced dwordx4 at base+lane*16B.
__global__ __launch_bounds__(256)
void cvt_kernel(const float* __restrict__ X, short* __restrict__ Xb) {
    int i    = blockIdx.x * 256 + threadIdx.x;   // 0 .. 2^20-1
    int lane = i & 63;
    int ks   = (i >> 6) & 7;
    int g    = (i >> 9) & 255;
    int b    = i >> 17;
    int ln   = lane & 15, kq = lane >> 4;
    const float* src = X + ((size_t)(b * 4096 + g * 16 + ln) * 256 + ks * 32 + kq * 8);
    float4 v0 = ((const float4*)src)[0];
    float4 v1 = ((const float4*)src)[1];
    bf16x8 o;
    o[0] = f2bf(v0.x); o[1] = f2bf(v0.y); o[2] = f2bf(v0.z); o[3] = f2bf(v0.w);
    o[4] = f2bf(v1.x); o[5] = f2bf(v1.y); o[6] = f2bf(v1.z); o[7] = f2bf(v1.w);
    *(bf16x8*)(Xb + ((size_t)b << 20) + g * 4096 + ks * 512 + lane * 8) = o;
}

// R14 = R13 + T15 deferred-bins: bins of tile nt-1 execute BETWEEN the MFMA
// half-clusters of tile nt (no data dependency), so the VALU/DS bins work
// fills MFMA issue/latency gaps instead of serializing after them. R7's null
// on this technique was the wrong regime (DS-slab-saturated); R13's slab-free
// loop is the right one. Even/odd acc naming keeps indexing static (rule #20).
__global__ __launch_bounds__(THREADS, 2)   // 8 waves = 2/SIMD; cap 256
void scpp_kernel(const short* __restrict__ X, float* __restrict__ out) {
    extern __shared__ unsigned int hist[];   // 16384 words = 64 KB

    const int t    = threadIdx.x;
    const int wave = t >> 6;           // 0..7
    const int lane = t & 63;
    const int q    = lane >> 4;        // quad 0..3
    const int ln   = lane & 15;
    const int h    = wave >> 2;        // row-half: rows m0 + h*64 .. +63
    const int cg   = wave & 3;         // col-group: cols nt*64 + cg*16 .. +15
    const int bid  = blockIdx.x;       // 0..255 -> 1 block/CU, zero tail
    const int batch = bid & 7;         // XCD-batch pinning
    const int m0    = (bid >> 3) * ROWS;
    const short* Xb = X + ((size_t)batch << 20);

    // zero histograms: 16384 words / 512 threads
    #pragma unroll
    for (int i = 0; i < (ROWS * WORDS) / THREADS; ++i)
        hist[t + THREADS * i] = 0u;

    // A fragments: 4 strips of 16 rows; coalesced fragment loads; AGPR-resident.
    bf16x8 af[4][8];
    {
        #pragma unroll
        for (int s = 0; s < 4; ++s) {
            const short* ap = Xb + (size_t)((m0 >> 4) + h * 4 + s) * 4096 + lane * 8;
            #pragma unroll
            for (int ks = 0; ks < 8; ++ks)
                af[s][ks] = *(const bf16x8*)(ap + ks * 512);
        }
        #pragma unroll
        for (int s = 0; s < 4; ++s)
            #pragma unroll
            for (int ks = 0; ks < 8; ++ks)
                asm volatile("" : "+v"(af[s][ks]));   // opaque: blocks remat
    }
    __syncthreads();   // hist zeros visible before atomics

    // bin transform: b = (v/256 - LO) * BINS/RANGE == v*scale + off
    const float scale = ((float)BINS / RANGE) / 256.0f;
    const float off   = -LO * ((float)BINS / RANGE);

    // loop-invariant per-strip histogram row pointer + bank swizzle
    unsigned int* Hrow[4];
    unsigned      swzr[4];
    #pragma unroll
    for (int s = 0; s < 4; ++s) {
        int row = h * 64 + s * 16 + ln;
        Hrow[s] = &hist[row * WORDS];
        swzr[s] = (unsigned)((row * 9) & 31);
    }

    // B fragment base for tile nt (coalesced: base + lane*16B)
    auto bptr = [&](int nt) {
        return Xb + (size_t)(nt * 4 + cg) * 4096 + lane * 8;
    };
    auto load4 = [&](bf16x8* d, const short* p, int ks0) {
        #pragma unroll
        for (int j = 0; j < 4; ++j)
            d[j] = *(const bf16x8*)(p + (ks0 + j) * 512);
    };
    auto mfmaH = [&](f32x4* acc, const bf16x8* bx, int ks0) {
        __builtin_amdgcn_s_setprio(1);
        #pragma unroll
        for (int j = 0; j < 4; ++j)
            #pragma unroll
            for (int s = 0; s < 4; ++s)   // swapped: bb as A, af as B -> D^T
                acc[s] = __builtin_amdgcn_mfma_f32_16x16x32_bf16(bx[j], af[s][ks0 + j], acc[s], 0, 0, 0);
        __builtin_amdgcn_s_setprio(0);
    };
    auto zero4 = [&](f32x4* acc) {
        #pragma unroll
        for (int s = 0; s < 4; ++s) acc[s] = f32x4{0.f, 0.f, 0.f, 0.f};
    };
    // bin 2 strips (8 elements) of a finished accumulator
    auto binsH = [&](const f32x4* acc, int sbase) {
        #pragma unroll
        for (int s2 = 0; s2 < 2; ++s2) {
            const int s = sbase + s2;
            #pragma unroll
            for (int reg = 0; reg < 4; ++reg) {
                int b  = (int)__builtin_amdgcn_fmed3f(
                             acc[s][reg] * scale + off, 0.0f, 511.0f);
                int pw = (b >> 2) ^ swzr[s];
                atomicAdd(&Hrow[s][pw], 1u << ((b & 3) << 3));
            }
        }
    };

    // K-loop: register ping-pong (bA/bB current, bA2/bB2 next) + deferred
    // bins of the previous tile interleaved into the current tile's MFMAs.
    f32x4 accE[4], accO[4];
    bf16x8 bA[4], bB[4], bA2[4], bB2[4];

    load4(bA, bptr(0), 0); load4(bB, bptr(0), 4);
    zero4(accE);
    mfmaH(accE, bA, 0);  load4(bA2, bptr(1), 0);
    mfmaH(accE, bB, 4);  load4(bB2, bptr(1), 4);

    for (int nt = 1; nt < 63; nt += 2) {
        zero4(accO);                                     // tile nt -> accO; bins nt-1
        mfmaH(accO, bA2, 0);  load4(bA, bptr(nt + 1), 0);  binsH(accE, 0);
        mfmaH(accO, bB2, 4);  load4(bB, bptr(nt + 1), 4);  binsH(accE, 2);
        zero4(accE);                                     // tile nt+1 -> accE; bins nt
        mfmaH(accE, bA, 0);   load4(bA2, bptr(nt + 2), 0); binsH(accO, 0);
        mfmaH(accE, bB, 4);   load4(bB2, bptr(nt + 2), 4); binsH(accO, 2);
    }
    // tail: bA2/bB2 hold tile 63; accE holds tile 62 (unbinned)
    zero4(accO);
    mfmaH(accO, bA2, 0);  binsH(accE, 0);
    mfmaH(accO, bB2, 4);  binsH(accE, 2);
    binsH(accO, 0);
    binsH(accO, 2);
    __syncthreads();   // all waves' atomics visible

    // epilogue, in-register per wave: rows 16w .. 16w+15 (u8 unpack)
    const float binw = RANGE / (float)BINS;
    #pragma unroll
    for (int rr = 0; rr < 16; ++rr) {
        const int r = wave * 16 + rr;
        const unsigned int msk = (unsigned int)(r * 9) & 31u;
        const unsigned int* H = &hist[r * WORDS];
        // lane L holds logical words 2L..2L+1 = bins 8L..8L+7 (un-swizzle)
        int cnt[8];
        #pragma unroll
        for (int i2 = 0; i2 < 2; ++i2) {
            unsigned int wd = H[(unsigned int)(2 * lane + i2) ^ msk];
            cnt[4 * i2 + 0] = (int)(wd & 0xFFu);
            cnt[4 * i2 + 1] = (int)((wd >> 8)  & 0xFFu);
            cnt[4 * i2 + 2] = (int)((wd >> 16) & 0xFFu);
            cnt[4 * i2 + 3] = (int)((wd >> 24) & 0xFFu);
        }
        int local = 0;
        #pragma unroll
        for (int u = 0; u < 8; ++u) local += cnt[u];
        // suffix-sum over lanes
        int suf = local;
        #pragma unroll
        for (int o2 = 1; o2 < 64; o2 <<= 1) {
            int o = __shfl_down(suf, o2, 64);
            if (lane + o2 < 64) suf += o;
        }
        int run = suf - local;
        int s[8];                       // s[u] = S[8*lane+u] = #values >= edge
        #pragma unroll
        for (int u = 7; u >= 0; --u) { run += cnt[u]; s[u] = run; }

        // answer 256 queries for this row: lane handles i = qq*64 + lane
        #pragma unroll
        for (int qq = 0; qq < 4; ++qq) {
            int i = qq * 64 + lane;
            float rv = 1.0f + (float)i * (4094.0f / 255.0f);
            int k = (int)rintf(rv) + 1;   // k-th largest, k in [2, 4096]
            int Lo = 0;
            #pragma unroll
            for (int st = 32; st >= 1; st >>= 1) {
                int cand = Lo + st;       // always <= 63
                int v = __shfl(s[0], cand, 64);
                if (v >= k) Lo = cand;
            }
            int j8 = 0;
            #pragma unroll
            for (int u = 0; u < 8; ++u) {
                int v = __shfl(s[u], Lo, 64);
                j8 += (v >= k) ? 1 : 0;
            }
            int j = 8 * Lo + j8 - 1;
            out[(size_t)(batch * 4096 + m0 + r) * 256 + i] = LO + ((float)j + 0.5f) * binw;
        }
    }
}

extern "C" void kernel_launch(void* const* d_in, const int* in_sizes, int n_in,
                              void* d_out, int out_size, void* d_ws, size_t ws_size,
                              hipStream_t stream) {
    static int attr_set = 0;
    if (!attr_set) {   // one-time, host-side, not a stream op (capture-safe)
        (void)hipFuncSetAttribute((const void*)scpp_kernel,
                                  hipFuncAttributeMaxDynamicSharedMemorySize, 65536);
        attr_set = 1;
    }
    const float* x = (const float*)d_in[0];
    float* out = (float*)d_out;
    short* xb = (short*)d_ws;                              // 16 MB blocked bf16
    hipLaunchKernelGGL(cvt_kernel, dim3(4096), dim3(256), 0, stream, x, xb);
    hipLaunchKernelGGL(scpp_kernel, dim3(256), dim3(THREADS), 65536, stream, xb, out);
}